// Round 1
// baseline (193.584 us; speedup 1.0000x reference)
//
#include <hip/hip_runtime.h>

#define H 64
#define NEDGE 50000
#define NNODE 12000
#define EPAD 50176

typedef _Float16 f16;
typedef _Float16 h8 __attribute__((ext_vector_type(8)));
typedef float f4 __attribute__((ext_vector_type(4)));
typedef float fv16 __attribute__((ext_vector_type(16)));

// workspace layout (bytes)
#define O_EDGEH 0ull            // edge f16 padded [50176][64]        = 6,422,528
#define O_W2G   6422528ull      // swizzled W2 f16 (64 chunks x 16KB) = 1,048,576
#define O_B2G   7471104ull      // swizzled b2 f16 (K=64 chunk, 8KB)  — MUST follow w2g (tail DMA)
#define O_W1G   7479296ull      // swizzled W1 f16 (16KB) — absorbs b2g-chunk 8KB overread
#define O_WG    7495680ull      // GRU combined weights f16 (64KB)
#define O_AGG   7561216ull      // agg f32 [12000][64]                = 3,072,000

__device__ __forceinline__ void async16(const void* g, void* l) {
  __builtin_amdgcn_global_load_lds((const __attribute__((address_space(1))) void*)g,
                                   (__attribute__((address_space(3))) void*)l, 16, 0, 0);
}

__device__ __forceinline__ fv16 zero16() {
  fv16 z;
#pragma unroll
  for (int i = 0; i < 16; ++i) z[i] = 0.f;
  return z;
}

// ---------------- prep: agg zero, edge->f16, W2/b2/W1/Wgru -> 32x32x16 MFMA-B granule order
// w2g: chunk h in [0,64); granule g=(s*2+nh)*64+l, elem i: W2[(h*64 + nh*32+(l&31))*128 + s*16+((l>>5)<<3)+i]
// b2g: granule g=(s*2+nh)*64+l (s<4), elem i: b2[(s*16+((l>>5)<<3)+i)*64 + nh*32+(l&31)]
// w1g: granule g=(s*4+nt)*64+l (s<4,nt<4), elem i: W1[(nt*32+(l&31))*64 + s*16+((l>>5)<<3)+i]
__global__ __launch_bounds__(256) void k_prep(const float* __restrict__ edge, const float* __restrict__ W1,
                                              const float* __restrict__ W2, const float* __restrict__ b2,
                                              const float* __restrict__ Wih, const float* __restrict__ Whh,
                                              f16* __restrict__ edgeh, f16* __restrict__ w1g, f16* __restrict__ w2g,
                                              f16* __restrict__ b2g, f16* __restrict__ wg, float* __restrict__ agg) {
  int bid = blockIdx.x;
  int t = threadIdx.x;
  if (bid < 750) {  // agg zero
    int id = bid * 256 + t;
    *(f4*)(agg + (long)id * 4) = (f4){0.f, 0.f, 0.f, 0.f};
    return;
  }
  if (bid < 2318) {  // edgeh cast, 8 elems/thread (EPAD rows, pad zeroed)
    long id8 = (long)(bid - 750) * 256 + t;
    long e = id8 >> 3;
    int c = (int)(id8 & 7) * 8;
    h8 o = {};
    if (e < NEDGE) {
      const float* p = edge + e * 64 + c;
      f4 v0 = *(const f4*)p, v1 = *(const f4*)(p + 4);
#pragma unroll
      for (int j = 0; j < 4; ++j) { o[j] = (f16)v0[j]; o[4 + j] = (f16)v1[j]; }
    }
    *(h8*)(edgeh + e * 64 + c) = o;
    return;
  }
  if (bid < 4366) {  // w2g: 524288 f16
    int id = (bid - 2318) * 256 + t;
    int i = id & 7, l = (id >> 3) & 63, nh = (id >> 9) & 1, s = (id >> 10) & 7, h = id >> 13;
    int n = nh * 32 + (l & 31), j = s * 16 + ((l >> 5) << 3) + i;
    w2g[id] = (f16)W2[(h * 64 + n) * 128 + j];
    return;
  }
  if (bid < 4382) {  // b2g: 4096 f16
    int id = (bid - 4366) * 256 + t;
    int i = id & 7, l = (id >> 3) & 63, nh = (id >> 9) & 1, s = id >> 10;
    int n = nh * 32 + (l & 31), k = s * 16 + ((l >> 5) << 3) + i;
    b2g[id] = (f16)b2[k * 64 + n];
    return;
  }
  if (bid < 4414) {  // w1g: 8192 f16
    int id = (bid - 4382) * 256 + t;
    int i = id & 7, l = (id >> 3) & 63, nt = (id >> 9) & 3, s = id >> 11;
    int n = nt * 32 + (l & 31), k = s * 16 + ((l >> 5) << 3) + i;
    w1g[id] = (f16)W1[n * 64 + k];
    return;
  }
  // wg: GRU combined B matrix [128k][256n] in 16x16x32 granule order, 32768 f16
  {
    int id = (bid - 4414) * 256 + t;
    int ii = id & 7, l = (id >> 3) & 63, tt = (id >> 9) & 15, s = id >> 13;
    int k = s * 32 + ((l >> 4) << 3) + ii, n = tt * 16 + (l & 15);
    float v;
    if (n < 128) v = (k < 64) ? Wih[n * 64 + k] : Whh[n * 64 + (k - 64)];
    else if (n < 192) v = (k < 64) ? Wih[n * 64 + k] : 0.f;
    else v = (k < 64) ? 0.f : Whh[(n - 64) * 64 + (k - 64)];
    wg[id] = (f16)v;
  }
}

// ---------------- fused msg kernel: 128 edges/block, K(h)-split x2 across blocks for occupancy.
// blockIdx: e-tile = bid>>1, h-half = bid&1 (h in [hs*32, hs*32+32)). Partial sums atomicAdd to agg,
// so the K-split is correctness-free; b2 bias tail applied only by the hs=1 block.
// 4 waves 2Mx2N (wave M=64, N=32), 32x32x16 MFMA. eh computed in-kernel via MFMA; eh fragments
// register-resident; B double-buffered in LDS (16KB chunks) via global_load_lds.
// LDS 52736 B -> 3 blocks/CU; grid 784 ~= 3.06 blocks/CU (vs 392 = 1.5 before: waves/SIMD 1 -> 3,
// so barrier/vmcnt drains of one block hide under the other blocks' MFMA).
__global__ __launch_bounds__(256, 3) void k_msg(const float* __restrict__ node,
                                                const int* __restrict__ src, const int* __restrict__ dst,
                                                const f16* __restrict__ edgeh, const f16* __restrict__ w1g,
                                                const f16* __restrict__ w2g, const float* __restrict__ b1,
                                                float* __restrict__ agg) {
  // [0,32768) bbuf dbuf (K-loop) / eh_s (phases 1-2, 128 rows x 256B)
  // [32768,51200) vT f16 [128 e][72] (pitch 144B, granule (e,hb) = v[e][8hb..8hb+7])
  // [51200,51712) ssrc | [51712,52224) sdst | [52224,52736) b1s
  __shared__ __align__(16) char lds[52736];
  f16* eh_s = (f16*)lds;
  char* bbuf = lds;
  f16* vT = (f16*)(lds + 32768);
  int* ssrc = (int*)(lds + 51200);
  int* sdst = (int*)(lds + 51712);
  float* b1s = (float*)(lds + 52224);

  int t = threadIdx.x;
  int bid = blockIdx.x;
  int e_base = (bid >> 1) * 128;
  int hs = bid & 1;  // h-split half: 0 -> h in [0,32), 1 -> h in [32,64) + bias tail

  // ---- phase 0: indices, b1, v gather -> vT
  if (t < 128) {
    int eg = e_base + t;
    bool valid = eg < NEDGE;
    ssrc[t] = valid ? src[eg] : 0;
    sdst[t] = valid ? dst[eg] : 0;
  } else {
    b1s[t - 128] = b1[t - 128];
  }
  {
    int e = t >> 1, half = t & 1;
    int eg = e_base + e;
    int si = (eg < NEDGE) ? src[eg] : 0;
    const f4* nr = (const f4*)(node + (long)si * 64 + half * 32);
#pragma unroll
    for (int b = 0; b < 4; ++b) {
      f4 v0 = nr[b * 2], v1 = nr[b * 2 + 1];
      h8 pk;
#pragma unroll
      for (int m = 0; m < 4; ++m) { pk[m] = (f16)v0[m]; pk[4 + m] = (f16)v1[m]; }
      *(h8*)(vT + e * 72 + (half * 4 + b) * 8) = pk;
    }
  }
  __syncthreads();

  int wave = t >> 6, lane = t & 63;
  int wm = wave & 1, wn = wave >> 1;
  int l31 = lane & 31, lh = lane >> 5;

  // ---- phase 1: eh = relu(edge @ W1^T + b1), M=128/N=128/K=64, wave tile 64x64
  {
    h8 afr[2][4];
#pragma unroll
    for (int mt = 0; mt < 2; ++mt)
#pragma unroll
      for (int s = 0; s < 4; ++s)
        afr[mt][s] = *(const h8*)(edgeh + (long)(e_base + wm * 64 + mt * 32 + l31) * 64 + s * 16 + lh * 8);
    h8 bfr[2][4];
#pragma unroll
    for (int nt = 0; nt < 2; ++nt)
#pragma unroll
      for (int s = 0; s < 4; ++s)
        bfr[nt][s] = *(const h8*)(w1g + ((s * 4 + wn * 2 + nt) * 64 + lane) * 8);
    fv16 acc_eh[2][2];
#pragma unroll
    for (int mt = 0; mt < 2; ++mt)
#pragma unroll
      for (int nt = 0; nt < 2; ++nt) acc_eh[mt][nt] = zero16();
#pragma unroll
    for (int s = 0; s < 4; ++s)
#pragma unroll
      for (int mt = 0; mt < 2; ++mt)
#pragma unroll
        for (int nt = 0; nt < 2; ++nt)
          acc_eh[mt][nt] = __builtin_amdgcn_mfma_f32_32x32x16_f16(afr[mt][s], bfr[nt][s], acc_eh[mt][nt], 0, 0, 0);
    // write eh tile to LDS, swizzled granules, + b1 + relu
#pragma unroll
    for (int mt = 0; mt < 2; ++mt)
#pragma unroll
      for (int nt = 0; nt < 2; ++nt)
#pragma unroll
        for (int r = 0; r < 16; ++r) {
          int row = (r & 3) + 8 * (r >> 2) + 4 * lh;
          int e = wm * 64 + mt * 32 + row;
          int n = wn * 64 + nt * 32 + l31;
          float val = fmaxf(acc_eh[mt][nt][r] + b1s[n], 0.f);
          int o = n >> 3;
          eh_s[e * 128 + ((o ^ (e & 15)) << 3) + (n & 7)] = (f16)val;
        }
  }
  __syncthreads();

  // ---- phase 2: eh fragments -> registers (j period 128 in K)
  h8 ehreg[2][8];
#pragma unroll
  for (int mt = 0; mt < 2; ++mt) {
    int e = wm * 64 + mt * 32 + l31;
#pragma unroll
    for (int s = 0; s < 8; ++s) {
      int o = (s * 2 + lh) ^ (e & 15);
      ehreg[mt][s] = *(const h8*)(eh_s + e * 128 + o * 8);
    }
  }
  __syncthreads();  // eh_s dead -> bbuf region free

  // prologue: DMA chunk h0 (16KB). h0 even for both halves -> always buf 0.
  const char* w2b = (const char*)w2g;
  int h0 = hs << 5;
#pragma unroll
  for (int r = 0; r < 4; ++r) async16(w2b + (long)h0 * 16384 + r * 4096 + t * 16, bbuf + r * 4096 + t * 16);

  // ---- phase 3: 32 h iterations (K=128 each), B LDS double-buffered
  fv16 acc[2];
  acc[0] = zero16(); acc[1] = zero16();
  const f16* vrow0 = vT + (wm * 64 + l31) * 72;
  const f16* vrow1 = vT + (wm * 64 + 32 + l31) * 72;

#pragma unroll 1
  for (int hb = hs * 4; hb < hs * 4 + 4; ++hb) {
    h8 vh0 = *(const h8*)(vrow0 + hb * 8);
    h8 vh1 = *(const h8*)(vrow1 + hb * 8);
#pragma unroll
    for (int hh = 0; hh < 8; ++hh) {
      int h = hb * 8 + hh;
      __syncthreads();  // chunk h landed; buffer (h+1)&1's readers retired
      if (h != 31 || hs) {  // hs=0 must NOT prefetch past its range: outstanding DMA at endpgm
                            // would land in the next workgroup's LDS. hs=1 h=63 loads b2g
                            // chunk (+8KB overread into w1g: unused).
        const char* gsrc = w2b + (long)(h + 1) * 16384;
        char* ldst = bbuf + ((h + 1) & 1) * 16384;
#pragma unroll
        for (int r = 0; r < 4; ++r) async16(gsrc + r * 4096 + t * 16, ldst + r * 4096 + t * 16);
      }
      const f16* bp = (const f16*)(bbuf + (h & 1) * 16384) + (wn * 64 + lane) * 8;
      f16 v0 = vh0[hh], v1 = vh1[hh];
#pragma unroll
      for (int s = 0; s < 8; ++s) {
        h8 bf = *(const h8*)(bp + s * 1024);
        h8 a0 = ehreg[0][s] * v0;
        acc[0] = __builtin_amdgcn_mfma_f32_32x32x16_f16(a0, bf, acc[0], 0, 0, 0);
        h8 a1 = ehreg[1][s] * v1;
        acc[1] = __builtin_amdgcn_mfma_f32_32x32x16_f16(a1, bf, acc[1], 0, 0, 0);
      }
    }
  }
  // ---- bias tail chunk (b2, K=64; in bbuf[0] from h=63 prefetch): A = v directly. hs=1 only.
  if (hs) {
    __syncthreads();
    const f16* bp = (const f16*)bbuf + (wn * 64 + lane) * 8;
#pragma unroll
    for (int s = 0; s < 4; ++s) {
      h8 bf = *(const h8*)(bp + s * 1024);
      h8 a0 = *(const h8*)(vrow0 + (s * 2 + lh) * 8);
      h8 a1 = *(const h8*)(vrow1 + (s * 2 + lh) * 8);
      acc[0] = __builtin_amdgcn_mfma_f32_32x32x16_f16(a0, bf, acc[0], 0, 0, 0);
      acc[1] = __builtin_amdgcn_mfma_f32_32x32x16_f16(a1, bf, acc[1], 0, 0, 0);
    }
  }

  // ---- epilogue: atomic scatter to agg[dst]. col n = wn*32 + l31
  int n = wn * 32 + l31;
#pragma unroll
  for (int mt = 0; mt < 2; ++mt)
#pragma unroll
    for (int r = 0; r < 16; ++r) {
      int el = wm * 64 + mt * 32 + (r & 3) + 8 * (r >> 2) + 4 * lh;
      if (e_base + el < NEDGE)
        atomicAdd(&agg[(long)sdst[el] * 64 + n], acc[mt][r]);
    }
}

// ---------------- GRU + LayerNorm via MFMA: 128 nodes/block, 4 waves M-split.
__global__ __launch_bounds__(256) void k_node(const float* __restrict__ agg, const float* __restrict__ hid,
                                              const f16* __restrict__ wg,
                                              const float* __restrict__ bih, const float* __restrict__ bhh,
                                              const float* __restrict__ gamma, const float* __restrict__ beta,
                                              float* __restrict__ out) {
  __shared__ __align__(16) f16 xh_s[128 * 136];
  __shared__ float bsum[128], bin_s[64], bhn_s[64], gam_s[64], bet_s[64];
  int t = threadIdx.x;
  int n0 = blockIdx.x * 128;

  if (t < 128) bsum[t] = bih[t] + bhh[t];
  else if (t < 192) bin_s[t - 128] = bih[t];
  else bhn_s[t - 192] = bhh[t - 64];
  if (t < 64) gam_s[t] = gamma[t];
  else if (t < 128) bet_s[t - 64] = beta[t - 64];

  {  // stage A = [relu(agg) | hid] as f16
    int m = t >> 1, half = t & 1;
    int mg = n0 + m;
    bool vld = mg < NNODE;
    const float* sp = half ? (hid + (long)mg * 64) : (agg + (long)mg * 64);
#pragma unroll
    for (int jj = 0; jj < 8; ++jj) {
      f4 v0 = {0, 0, 0, 0}, v1 = {0, 0, 0, 0};
      if (vld) { v0 = *(const f4*)(sp + jj * 8); v1 = *(const f4*)(sp + jj * 8 + 4); }
      h8 pk;
#pragma unroll
      for (int m2 = 0; m2 < 4; ++m2) {
        pk[m2] = (f16)(half ? v0[m2] : fmaxf(v0[m2], 0.f));
        pk[4 + m2] = (f16)(half ? v1[m2] : fmaxf(v1[m2], 0.f));
      }
      *(h8*)(xh_s + m * 136 + half * 64 + jj * 8) = pk;
    }
  }
  __syncthreads();

  int wave = t >> 6, lane = t & 63;
  int l15 = lane & 15, lq = lane >> 4;

  f4 acc[2][16];
#pragma unroll
  for (int g = 0; g < 2; ++g)
#pragma unroll
    for (int tt = 0; tt < 16; ++tt) acc[g][tt] = (f4){0.f, 0.f, 0.f, 0.f};

#pragma unroll
  for (int s = 0; s < 4; ++s) {
    h8 a0 = *(const h8*)(xh_s + (wave * 32 + l15) * 136 + s * 32 + lq * 8);
    h8 a1 = *(const h8*)(xh_s + (wave * 32 + 16 + l15) * 136 + s * 32 + lq * 8);
#pragma unroll
    for (int tt = 0; tt < 16; ++tt) {
      h8 b = *(const h8*)(wg + ((s * 16 + tt) * 64 + lane) * 8);
      acc[0][tt] = __builtin_amdgcn_mfma_f32_16x16x32_f16(a0, b, acc[0][tt], 0, 0, 0);
      acc[1][tt] = __builtin_amdgcn_mfma_f32_16x16x32_f16(a1, b, acc[1][tt], 0, 0, 0);
    }
  }

#pragma unroll
  for (int g = 0; g < 2; ++g)
#pragma unroll
    for (int r = 0; r < 4; ++r) {
      int mg = n0 + wave * 32 + g * 16 + lq * 4 + r;
      bool vld = mg < NNODE;
      float o[4], ssum = 0.f, s2 = 0.f;
#pragma unroll
      for (int t0 = 0; t0 < 4; ++t0) {
        int f = t0 * 16 + l15;
        float rpre = acc[g][t0][r] + bsum[f];
        float zpre = acc[g][4 + t0][r] + bsum[64 + f];
        float ginv = acc[g][8 + t0][r] + bin_s[f];
        float ghnv = acc[g][12 + t0][r] + bhn_s[f];
        float rr = 1.f / (1.f + __expf(-rpre));
        float zz = 1.f / (1.f + __expf(-zpre));
        float hv = vld ? hid[(long)mg * 64 + f] : 0.f;
        float nn = tanhf(ginv + rr * ghnv);
        float oo = (1.f - zz) * nn + zz * hv;
        o[t0] = oo; ssum += oo; s2 += oo * oo;
      }
#pragma unroll
      for (int d = 1; d < 16; d <<= 1) {
        ssum += __shfl_xor(ssum, d);
        s2 += __shfl_xor(s2, d);
      }
      float mu = ssum * (1.f / 64.f);
      float var = s2 * (1.f / 64.f) - mu * mu;
      float rstd = rsqrtf(var + 1e-5f);
      if (vld)
#pragma unroll
        for (int t0 = 0; t0 < 4; ++t0) {
          int f = t0 * 16 + l15;
          out[(long)mg * 64 + f] = (o[t0] - mu) * rstd * gam_s[f] + bet_s[f];
        }
    }
}

extern "C" void kernel_launch(void* const* d_in, const int* in_sizes, int n_in,
                              void* d_out, int out_size, void* d_ws, size_t ws_size,
                              hipStream_t stream) {
  const float* node = (const float*)d_in[0];
  const float* edge = (const float*)d_in[1];
  const float* hid = (const float*)d_in[2];
  const int* src = (const int*)d_in[3];
  const int* dst = (const int*)d_in[4];
  const float* W1 = (const float*)d_in[5];
  const float* b1 = (const float*)d_in[6];
  const float* W2 = (const float*)d_in[7];
  const float* b2 = (const float*)d_in[8];
  const float* Wih = (const float*)d_in[9];
  const float* Whh = (const float*)d_in[10];
  const float* bih = (const float*)d_in[11];
  const float* bhh = (const float*)d_in[12];
  const float* gamma = (const float*)d_in[13];
  const float* beta = (const float*)d_in[14];

  char* ws = (char*)d_ws;
  f16* edgeh = (f16*)(ws + O_EDGEH);
  f16* w2g = (f16*)(ws + O_W2G);
  f16* b2g = (f16*)(ws + O_B2G);
  f16* w1g = (f16*)(ws + O_W1G);
  f16* wg = (f16*)(ws + O_WG);
  float* agg = (float*)(ws + O_AGG);

  k_prep<<<4542, 256, 0, stream>>>(edge, W1, W2, b2, Wih, Whh, edgeh, w1g, w2g, b2g, wg, agg);
  k_msg<<<784, 256, 0, stream>>>(node, src, dst, edgeh, w1g, w2g, b1, agg);
  k_node<<<94, 256, 0, stream>>>(agg, hid, wg, bih, bhh, gamma, beta, (float*)d_out);
}